// Round 3
// baseline (860.959 us; speedup 1.0000x reference)
//
#include <hip/hip_runtime.h>
#include <hip/hip_bf16.h>

// MC-Dropout eval-path masking: out[b, f] = in[b, f] * mask[f]
// in: (32768, 4096) fp32, mask: (4096,) fp32, out: (32768, 4096) fp32.
// Pure memory-bound streaming op: 512 MiB read + 512 MiB write per call.
// float4 vectorized, grid-stride, mask load hoisted (loop-invariant).

#define LAYER_SIZE 4096
#define MASK_VEC4  (LAYER_SIZE / 4)   // 1024 float4s per row

__global__ void __launch_bounds__(256)
mcdropout_mask_kernel(const float4* __restrict__ in,
                      const float4* __restrict__ mask,
                      float4* __restrict__ out,
                      int n4) {
    const int stride = gridDim.x * blockDim.x;
    int i = blockIdx.x * blockDim.x + threadIdx.x;
    if (i >= n4) return;

    // stride (2048*256 = 524288) is a multiple of MASK_VEC4 (1024), so the
    // mask vec-index is invariant across the grid-stride loop: hoist it.
    const float4 m = mask[i & (MASK_VEC4 - 1)];

    for (; i < n4; i += stride) {
        float4 v = in[i];
        v.x *= m.x;
        v.y *= m.y;
        v.z *= m.z;
        v.w *= m.w;
        out[i] = v;
    }
}

extern "C" void kernel_launch(void* const* d_in, const int* in_sizes, int n_in,
                              void* d_out, int out_size, void* d_ws, size_t ws_size,
                              hipStream_t stream) {
    const float4* in   = (const float4*)d_in[0];   // (32768, 4096) fp32
    const float4* mask = (const float4*)d_in[1];   // (4096,) fp32
    float4* out = (float4*)d_out;

    const int n4 = out_size / 4;                   // 33,554,432 float4s

    // 2048 blocks x 256 threads: each thread grid-strides over 64 float4s.
    // Enough TLP to saturate HBM; stride stays a multiple of the mask period
    // (do NOT change blocks*threads off a multiple of 1024 without removing
    // the mask-hoist above).
    const int threads = 256;
    const int blocks  = 2048;
    mcdropout_mask_kernel<<<blocks, threads, 0, stream>>>(in, mask, out, n4);
}